// Round 1
// baseline (1090.615 us; speedup 1.0000x reference)
//
#include <hip/hip_runtime.h>

#define HIDDEN 1024
#define FF 2048
#define NEXP 8
#define NTOK 16384
#define NPAIR (2 * NTOK)

typedef short short8 __attribute__((ext_vector_type(8)));
typedef float f32x4 __attribute__((ext_vector_type(4)));

// fp32 -> bf16 bits, round-to-nearest-even
__device__ __forceinline__ unsigned short f2b(float f) {
  union { float f; unsigned int u; } v; v.f = f;
  unsigned int u = v.u;
  return (unsigned short)((u + 0x7fffu + ((u >> 16) & 1u)) >> 16);
}

// ---------------- workspace layout (bytes) ----------------
// w1t: [E][FF][HIDDEN] bf16   (N-major, K-contiguous)   32 MB
// w2t: [E][HIDDEN][FF] bf16                              32 MB
// h:   [NPAIR][FF] bf16                                 128 MB
// cnt: [E] int
// plist: [E][NTOK] int
// pw:  [NPAIR] float
#define W1T_OFF 0ull
#define W2T_OFF (W1T_OFF + (unsigned long long)NEXP * FF * HIDDEN * 2)
#define H_OFF   (W2T_OFF + (unsigned long long)NEXP * HIDDEN * FF * 2)
#define CNT_OFF (H_OFF + (unsigned long long)NPAIR * FF * 2)
#define PLIST_OFF (CNT_OFF + 256ull)
#define PW_OFF  (PLIST_OFF + (unsigned long long)NEXP * NTOK * 4)

__global__ void zero_out_k(float4* __restrict__ out) {
  out[(size_t)blockIdx.x * 256 + threadIdx.x] = float4{0.f, 0.f, 0.f, 0.f};
}

__global__ void zero_cnt_k(int* __restrict__ cnt) {
  if (threadIdx.x < NEXP) cnt[threadIdx.x] = 0;
}

// in: [E][R][C] f32  ->  out: [E][C][R] bf16
__global__ void transpose_cast_k(const float* __restrict__ in,
                                 unsigned short* __restrict__ out,
                                 int R, int C) {
  __shared__ float tile[32][33];
  const size_t eoff = (size_t)blockIdx.z * R * C;
  const float* inp = in + eoff;
  unsigned short* outp = out + eoff;
  const int c = threadIdx.x & 31;
  const int r0 = threadIdx.x >> 5;
  const int gr = blockIdx.y * 32, gc = blockIdx.x * 32;
#pragma unroll
  for (int i = 0; i < 4; i++) {
    int r = r0 + i * 8;
    tile[r][c] = inp[(size_t)(gr + r) * C + gc + c];
  }
  __syncthreads();
#pragma unroll
  for (int i = 0; i < 4; i++) {
    int r = r0 + i * 8;
    outp[(size_t)(gc + r) * R + gr + c] = f2b(tile[c][r]);
  }
}

// one wave per token: logits over 8 experts, top-2, renorm, scatter
__global__ void router_k(const float* __restrict__ x, const float* __restrict__ rw,
                         const float* __restrict__ rb, int* __restrict__ cnt,
                         int* __restrict__ plist, float* __restrict__ pw) {
  const int wid = threadIdx.x >> 6;
  const int lane = threadIdx.x & 63;
  const int t = blockIdx.x * 4 + wid;
  const float* xr = x + (size_t)t * HIDDEN;
  float acc[8];
#pragma unroll
  for (int e = 0; e < 8; e++) acc[e] = 0.f;
#pragma unroll
  for (int i = 0; i < 16; i++) {
    int hh = lane + 64 * i;
    float xv = xr[hh];
    const float4* rwp = reinterpret_cast<const float4*>(rw + (size_t)hh * 8);
    float4 a = rwp[0], b = rwp[1];
    acc[0] += xv * a.x; acc[1] += xv * a.y; acc[2] += xv * a.z; acc[3] += xv * a.w;
    acc[4] += xv * b.x; acc[5] += xv * b.y; acc[6] += xv * b.z; acc[7] += xv * b.w;
  }
#pragma unroll
  for (int off = 32; off; off >>= 1) {
#pragma unroll
    for (int e = 0; e < 8; e++) acc[e] += __shfl_xor(acc[e], off);
  }
  if (lane == 0) {
#pragma unroll
    for (int e = 0; e < 8; e++) acc[e] += rb[e];
    int i0 = 0; float m0 = acc[0];
#pragma unroll
    for (int e = 1; e < 8; e++) if (acc[e] > m0) { m0 = acc[e]; i0 = e; }
    int i1 = -1; float m1 = -1e30f;
#pragma unroll
    for (int e = 0; e < 8; e++) if (e != i0 && acc[e] > m1) { m1 = acc[e]; i1 = e; }
    float w0 = 1.f / (1.f + __expf(m1 - m0));
    float w1 = 1.f - w0;
    int p0 = atomicAdd(&cnt[i0], 1);
    plist[i0 * NTOK + p0] = 2 * t;
    pw[2 * t] = w0;
    int p1 = atomicAdd(&cnt[i1], 1);
    plist[i1 * NTOK + p1] = 2 * t + 1;
    pw[2 * t + 1] = w1;
  }
}

// Grouped GEMM. PHASE 1: h[pair] = relu(x[token] @ w1t[e]^T + b1[e])  (K=1024,N=2048)
//              PHASE 2: out[token] += pw[pair] * (h[pair] @ w2t[e]^T + b2[e]) (K=2048,N=1024)
template <int PHASE>
__global__ __launch_bounds__(256)
void ffn_k(const float* __restrict__ x, const unsigned short* __restrict__ wT,
           const float* __restrict__ bias, const unsigned short* __restrict__ hin,
           unsigned short* __restrict__ hout, float* __restrict__ out,
           const int* __restrict__ cnt, const int* __restrict__ plist,
           const float* __restrict__ pw) {
  constexpr int K = (PHASE == 1) ? HIDDEN : FF;
  constexpr int N = (PHASE == 1) ? FF : HIDDEN;

  const int e = blockIdx.z;
  const int mcnt = cnt[e];
  const int m0g = blockIdx.x * 128;
  if (m0g >= mcnt) return;
  const int n0g = blockIdx.y * 128;
  const int mrem = mcnt - m0g;  // valid rows in tile (may exceed 128; cap below)

  __shared__ alignas(16) unsigned short As[128][40];
  __shared__ alignas(16) unsigned short Bs[128][40];
  __shared__ int rowpair[128];

  const int tid = threadIdx.x;
  if (tid < 128) rowpair[tid] = (tid < mrem) ? plist[e * NTOK + m0g + tid] : -1;
  __syncthreads();

  const int srow = tid >> 1;   // staging row 0..127
  const int shalf = tid & 1;   // 16-elem half
  const int mypair = rowpair[srow];
  const unsigned short* wTe = wT + (size_t)e * N * K;

  const int wid = tid >> 6;
  const int lane = tid & 63;
  const int wr = (wid >> 1) * 64;  // wave row offset in tile
  const int wc = (wid & 1) * 64;   // wave col offset
  const int fr = lane & 15;
  const int fg = lane >> 4;

  f32x4 acc[4][4];
#pragma unroll
  for (int i = 0; i < 4; i++)
#pragma unroll
    for (int j = 0; j < 4; j++) acc[i][j] = f32x4{0.f, 0.f, 0.f, 0.f};

  for (int kt = 0; kt < K; kt += 32) {
    // ---- stage A (gathered rows, 16 elems/thread) ----
    if constexpr (PHASE == 1) {
      short8 v0, v1;
      if (mypair >= 0) {
        const float* src = x + (size_t)(mypair >> 1) * HIDDEN + kt + shalf * 16;
#pragma unroll
        for (int i = 0; i < 4; i++) {
          float4 f = reinterpret_cast<const float4*>(src)[i];
          short8& v = (i < 2) ? v0 : v1;
          int b = (i & 1) * 4;
          v[b + 0] = (short)f2b(f.x); v[b + 1] = (short)f2b(f.y);
          v[b + 2] = (short)f2b(f.z); v[b + 3] = (short)f2b(f.w);
        }
      } else {
        v0 = short8{0,0,0,0,0,0,0,0}; v1 = v0;
      }
      *(short8*)&As[srow][shalf * 16] = v0;
      *(short8*)&As[srow][shalf * 16 + 8] = v1;
    } else {
      short8 v0, v1;
      if (mypair >= 0) {
        const unsigned short* src = hin + (size_t)mypair * FF + kt + shalf * 16;
        v0 = *(const short8*)src;
        v1 = *(const short8*)(src + 8);
      } else {
        v0 = short8{0,0,0,0,0,0,0,0}; v1 = v0;
      }
      *(short8*)&As[srow][shalf * 16] = v0;
      *(short8*)&As[srow][shalf * 16 + 8] = v1;
    }
    // ---- stage B (w rows, K-contiguous) ----
    {
      const unsigned short* src = wTe + (size_t)(n0g + srow) * K + kt + shalf * 16;
      *(short8*)&Bs[srow][shalf * 16] = *(const short8*)src;
      *(short8*)&Bs[srow][shalf * 16 + 8] = *(const short8*)(src + 8);
    }
    __syncthreads();

    short8 af[4], bf[4];
#pragma unroll
    for (int mi = 0; mi < 4; mi++) af[mi] = *(const short8*)&As[wr + mi * 16 + fr][fg * 8];
#pragma unroll
    for (int ni = 0; ni < 4; ni++) bf[ni] = *(const short8*)&Bs[wc + ni * 16 + fr][fg * 8];
#pragma unroll
    for (int mi = 0; mi < 4; mi++)
#pragma unroll
      for (int ni = 0; ni < 4; ni++)
        acc[mi][ni] = __builtin_amdgcn_mfma_f32_16x16x32_bf16(af[mi], bf[ni], acc[mi][ni], 0, 0, 0);
    __syncthreads();
  }

  // ---- epilogue ----
  float bv[4];
#pragma unroll
  for (int ni = 0; ni < 4; ni++) bv[ni] = bias[(size_t)e * N + n0g + wc + ni * 16 + fr];

#pragma unroll
  for (int mi = 0; mi < 4; mi++) {
#pragma unroll
    for (int r = 0; r < 4; r++) {
      int m = wr + mi * 16 + fg * 4 + r;
      if (m >= mrem) continue;
      int p = rowpair[m];
      if constexpr (PHASE == 1) {
        unsigned short* hr = hout + (size_t)p * FF + n0g;
#pragma unroll
        for (int ni = 0; ni < 4; ni++) {
          float v = acc[mi][ni][r] + bv[ni];
          hr[wc + ni * 16 + fr] = f2b(fmaxf(v, 0.f));
        }
      } else {
        float wgt = pw[p];
        float* orow = out + (size_t)(p >> 1) * HIDDEN + n0g;
#pragma unroll
        for (int ni = 0; ni < 4; ni++) {
          float v = (acc[mi][ni][r] + bv[ni]) * wgt;
          atomicAdd(&orow[wc + ni * 16 + fr], v);
        }
      }
    }
  }
}

extern "C" void kernel_launch(void* const* d_in, const int* in_sizes, int n_in,
                              void* d_out, int out_size, void* d_ws, size_t ws_size,
                              hipStream_t stream) {
  const float* x  = (const float*)d_in[0];
  const float* rw = (const float*)d_in[1];
  const float* rb = (const float*)d_in[2];
  const float* w1 = (const float*)d_in[3];
  const float* b1 = (const float*)d_in[4];
  const float* w2 = (const float*)d_in[5];
  const float* b2 = (const float*)d_in[6];
  float* out = (float*)d_out;
  char* ws = (char*)d_ws;

  unsigned short* w1t = (unsigned short*)(ws + W1T_OFF);
  unsigned short* w2t = (unsigned short*)(ws + W2T_OFF);
  unsigned short* h   = (unsigned short*)(ws + H_OFF);
  int* cnt   = (int*)(ws + CNT_OFF);
  int* plist = (int*)(ws + PLIST_OFF);
  float* pwt = (float*)(ws + PW_OFF);

  hipLaunchKernelGGL(zero_cnt_k, dim3(1), dim3(64), 0, stream, cnt);
  // out: 16384*1024 floats = 4,194,304 float4 = 16384 blocks * 256
  hipLaunchKernelGGL(zero_out_k, dim3(16384), dim3(256), 0, stream, (float4*)out);
  hipLaunchKernelGGL(transpose_cast_k, dim3(FF / 32, HIDDEN / 32, NEXP), dim3(256), 0, stream,
                     w1, w1t, HIDDEN, FF);
  hipLaunchKernelGGL(transpose_cast_k, dim3(HIDDEN / 32, FF / 32, NEXP), dim3(256), 0, stream,
                     w2, w2t, FF, HIDDEN);
  hipLaunchKernelGGL(router_k, dim3(NTOK / 4), dim3(256), 0, stream, x, rw, rb, cnt, plist, pwt);
  hipLaunchKernelGGL(ffn_k<1>, dim3(128, FF / 128, NEXP), dim3(256), 0, stream,
                     x, w1t, b1, (const unsigned short*)nullptr, h, (float*)nullptr,
                     cnt, plist, pwt);
  hipLaunchKernelGGL(ffn_k<2>, dim3(128, HIDDEN / 128, NEXP), dim3(256), 0, stream,
                     x, w2t, b2, h, (unsigned short*)nullptr, out,
                     cnt, plist, pwt);
}

// Round 2
// 679.983 us; speedup vs baseline: 1.6039x; 1.6039x over previous
//
#include <hip/hip_runtime.h>

#define HIDDEN 1024
#define FF 2048
#define NEXP 8
#define NTOK 16384
#define NPAIR (2 * NTOK)

typedef short short8 __attribute__((ext_vector_type(8)));
typedef float f32x4 __attribute__((ext_vector_type(4)));

// fp32 -> bf16 bits, round-to-nearest-even
__device__ __forceinline__ unsigned short f2b(float f) {
  union { float f; unsigned int u; } v; v.f = f;
  unsigned int u = v.u;
  return (unsigned short)((u + 0x7fffu + ((u >> 16) & 1u)) >> 16);
}

// ---------------- workspace layout (bytes) ----------------
#define W1T_OFF 0ull                                                      // [E][FF][HIDDEN] bf16, 32MB
#define W2T_OFF (W1T_OFF + (unsigned long long)NEXP * FF * HIDDEN * 2)    // [E][HIDDEN][FF] bf16, 32MB
#define H_OFF   (W2T_OFF + (unsigned long long)NEXP * HIDDEN * FF * 2)    // [NPAIR][FF] bf16, 128MB
#define XB_OFF  (H_OFF + (unsigned long long)NPAIR * FF * 2)              // [NTOK][HIDDEN] bf16, 32MB
#define CNT_OFF (XB_OFF + (unsigned long long)NTOK * HIDDEN * 2)          // [E] int
#define PLIST_OFF (CNT_OFF + 256ull)                                      // [E][NTOK] int
#define PW_OFF    (PLIST_OFF + (unsigned long long)NEXP * NTOK * 4)       // [NPAIR] float
#define TOPS_OFF  (PW_OFF + (unsigned long long)NPAIR * 4)                // [NTOK] int
#define W0_OFF    (TOPS_OFF + (unsigned long long)NTOK * 4)               // [NTOK] float

__global__ void zero_out_k(float4* __restrict__ out) {
  out[(size_t)blockIdx.x * 256 + threadIdx.x] = float4{0.f, 0.f, 0.f, 0.f};
}

__global__ void zero_cnt_k(int* __restrict__ cnt) {
  if (threadIdx.x < NEXP) cnt[threadIdx.x] = 0;
}

// x fp32 -> bf16, 8 elems/thread
__global__ void xcast_k(const float* __restrict__ x, unsigned short* __restrict__ xb) {
  const size_t i = ((size_t)blockIdx.x * 256 + threadIdx.x) * 8;
  float4 a = reinterpret_cast<const float4*>(x + i)[0];
  float4 b = reinterpret_cast<const float4*>(x + i)[1];
  short8 v;
  v[0] = (short)f2b(a.x); v[1] = (short)f2b(a.y); v[2] = (short)f2b(a.z); v[3] = (short)f2b(a.w);
  v[4] = (short)f2b(b.x); v[5] = (short)f2b(b.y); v[6] = (short)f2b(b.z); v[7] = (short)f2b(b.w);
  *reinterpret_cast<short8*>(xb + i) = v;
}

// in: [E][R][C] f32  ->  out: [E][C][R] bf16
__global__ void transpose_cast_k(const float* __restrict__ in,
                                 unsigned short* __restrict__ out,
                                 int R, int C) {
  __shared__ float tile[32][33];
  const size_t eoff = (size_t)blockIdx.z * R * C;
  const float* inp = in + eoff;
  unsigned short* outp = out + eoff;
  const int c = threadIdx.x & 31;
  const int r0 = threadIdx.x >> 5;
  const int gr = blockIdx.y * 32, gc = blockIdx.x * 32;
#pragma unroll
  for (int i = 0; i < 4; i++) {
    int r = r0 + i * 8;
    tile[r][c] = inp[(size_t)(gr + r) * C + gc + c];
  }
  __syncthreads();
#pragma unroll
  for (int i = 0; i < 4; i++) {
    int r = r0 + i * 8;
    outp[(size_t)(gc + r) * R + gr + c] = f2b(tile[c][r]);
  }
}

// one wave per token: logits over 8 experts, top-2, renorm. NO atomics.
__global__ void router_k(const float* __restrict__ x, const float* __restrict__ rw,
                         const float* __restrict__ rb, int* __restrict__ tops,
                         float* __restrict__ w0f) {
  const int wid = threadIdx.x >> 6;
  const int lane = threadIdx.x & 63;
  const int t = blockIdx.x * 4 + wid;
  const float* xr = x + (size_t)t * HIDDEN;
  float acc[8];
#pragma unroll
  for (int e = 0; e < 8; e++) acc[e] = 0.f;
#pragma unroll
  for (int i = 0; i < 16; i++) {
    int hh = lane + 64 * i;
    float xv = xr[hh];
    const float4* rwp = reinterpret_cast<const float4*>(rw + (size_t)hh * 8);
    float4 a = rwp[0], b = rwp[1];
    acc[0] += xv * a.x; acc[1] += xv * a.y; acc[2] += xv * a.z; acc[3] += xv * a.w;
    acc[4] += xv * b.x; acc[5] += xv * b.y; acc[6] += xv * b.z; acc[7] += xv * b.w;
  }
#pragma unroll
  for (int off = 32; off; off >>= 1) {
#pragma unroll
    for (int e = 0; e < 8; e++) acc[e] += __shfl_xor(acc[e], off);
  }
  if (lane == 0) {
#pragma unroll
    for (int e = 0; e < 8; e++) acc[e] += rb[e];
    int i0 = 0; float m0 = acc[0];
#pragma unroll
    for (int e = 1; e < 8; e++) if (acc[e] > m0) { m0 = acc[e]; i0 = e; }
    int i1 = -1; float m1 = -1e30f;
#pragma unroll
    for (int e = 0; e < 8; e++) if (e != i0 && acc[e] > m1) { m1 = acc[e]; i1 = e; }
    float w0 = 1.f / (1.f + __expf(m1 - m0));
    tops[t] = i0 | (i1 << 4);
    w0f[t] = w0;
  }
}

// block-aggregated scatter: 256 tokens/block, LDS histogram, 8 global atomics/block
__global__ __launch_bounds__(256)
void scatter_k(const int* __restrict__ tops, const float* __restrict__ w0f,
               int* __restrict__ cnt, int* __restrict__ plist, float* __restrict__ pw) {
  __shared__ int lcnt[NEXP];
  __shared__ int lbase[NEXP];
  const int tid = threadIdx.x;
  const int t = blockIdx.x * 256 + tid;
  if (tid < NEXP) lcnt[tid] = 0;
  __syncthreads();
  const int packed = tops[t];
  const int i0 = packed & 15, i1 = packed >> 4;
  const float w0 = w0f[t];
  const int s0 = atomicAdd(&lcnt[i0], 1);
  const int s1 = atomicAdd(&lcnt[i1], 1);
  __syncthreads();
  if (tid < NEXP) lbase[tid] = atomicAdd(&cnt[tid], lcnt[tid]);
  __syncthreads();
  plist[i0 * NTOK + lbase[i0] + s0] = 2 * t;
  plist[i1 * NTOK + lbase[i1] + s1] = 2 * t + 1;
  pw[2 * t] = w0;
  pw[2 * t + 1] = 1.f - w0;
}

// Grouped GEMM. PHASE 1: h[pair] = relu(xb[token] @ w1t[e]^T + b1[e])  (K=1024,N=2048)
//              PHASE 2: out[token] += pw[pair] * (h[pair] @ w2t[e]^T + b2[e]) (K=2048,N=1024)
template <int PHASE>
__global__ __launch_bounds__(256)
void ffn_k(const unsigned short* __restrict__ xb, const unsigned short* __restrict__ wT,
           const float* __restrict__ bias, const unsigned short* __restrict__ hin,
           unsigned short* __restrict__ hout, float* __restrict__ out,
           const int* __restrict__ cnt, const int* __restrict__ plist,
           const float* __restrict__ pw) {
  constexpr int K = (PHASE == 1) ? HIDDEN : FF;
  constexpr int N = (PHASE == 1) ? FF : HIDDEN;

  const int e = blockIdx.z;
  const int mcnt = cnt[e];
  const int m0g = blockIdx.x * 128;
  if (m0g >= mcnt) return;
  const int n0g = blockIdx.y * 128;
  const int mrem = mcnt - m0g;

  __shared__ alignas(16) unsigned short As[128][40];
  __shared__ alignas(16) unsigned short Bs[128][40];
  __shared__ int rowpair[128];

  const int tid = threadIdx.x;
  if (tid < 128) rowpair[tid] = (tid < mrem) ? plist[e * NTOK + m0g + tid] : -1;
  __syncthreads();

  const int srow = tid >> 1;   // staging row 0..127
  const int shalf = tid & 1;   // 16-elem half
  const int mypair = rowpair[srow];
  const unsigned short* wTe = wT + (size_t)e * N * K;
  const unsigned short* arow = nullptr;
  if (mypair >= 0)
    arow = (PHASE == 1) ? xb + (size_t)(mypair >> 1) * HIDDEN
                        : hin + (size_t)mypair * FF;

  const int wid = tid >> 6;
  const int lane = tid & 63;
  const int wr = (wid >> 1) * 64;
  const int wc = (wid & 1) * 64;
  const int fr = lane & 15;
  const int fg = lane >> 4;

  f32x4 acc[4][4];
#pragma unroll
  for (int i = 0; i < 4; i++)
#pragma unroll
    for (int j = 0; j < 4; j++) acc[i][j] = f32x4{0.f, 0.f, 0.f, 0.f};

  for (int kt = 0; kt < K; kt += 32) {
    // ---- stage A (gathered bf16 rows, 32 elems per 2 threads) ----
    {
      short8 v0 = short8{0,0,0,0,0,0,0,0}, v1 = v0;
      if (arow) {
        const unsigned short* src = arow + kt + shalf * 16;
        v0 = *(const short8*)src;
        v1 = *(const short8*)(src + 8);
      }
      *(short8*)&As[srow][shalf * 16] = v0;
      *(short8*)&As[srow][shalf * 16 + 8] = v1;
    }
    // ---- stage B (w rows, K-contiguous) ----
    {
      const unsigned short* src = wTe + (size_t)(n0g + srow) * K + kt + shalf * 16;
      *(short8*)&Bs[srow][shalf * 16] = *(const short8*)src;
      *(short8*)&Bs[srow][shalf * 16 + 8] = *(const short8*)(src + 8);
    }
    __syncthreads();

    short8 af[4], bf[4];
#pragma unroll
    for (int mi = 0; mi < 4; mi++) af[mi] = *(const short8*)&As[wr + mi * 16 + fr][fg * 8];
#pragma unroll
    for (int ni = 0; ni < 4; ni++) bf[ni] = *(const short8*)&Bs[wc + ni * 16 + fr][fg * 8];
#pragma unroll
    for (int mi = 0; mi < 4; mi++)
#pragma unroll
      for (int ni = 0; ni < 4; ni++)
        acc[mi][ni] = __builtin_amdgcn_mfma_f32_16x16x32_bf16(af[mi], bf[ni], acc[mi][ni], 0, 0, 0);
    __syncthreads();
  }

  // ---- epilogue ----
  float bv[4];
#pragma unroll
  for (int ni = 0; ni < 4; ni++) bv[ni] = bias[(size_t)e * N + n0g + wc + ni * 16 + fr];

#pragma unroll
  for (int mi = 0; mi < 4; mi++) {
#pragma unroll
    for (int r = 0; r < 4; r++) {
      int m = wr + mi * 16 + fg * 4 + r;
      if (m >= mrem) continue;
      int p = rowpair[m];
      if constexpr (PHASE == 1) {
        unsigned short* hr = hout + (size_t)p * FF + n0g;
#pragma unroll
        for (int ni = 0; ni < 4; ni++) {
          float v = acc[mi][ni][r] + bv[ni];
          hr[wc + ni * 16 + fr] = f2b(fmaxf(v, 0.f));
        }
      } else {
        float wgt = pw[p];
        float* orow = out + (size_t)(p >> 1) * HIDDEN + n0g;
#pragma unroll
        for (int ni = 0; ni < 4; ni++) {
          float v = (acc[mi][ni][r] + bv[ni]) * wgt;
          atomicAdd(&orow[wc + ni * 16 + fr], v);
        }
      }
    }
  }
}

extern "C" void kernel_launch(void* const* d_in, const int* in_sizes, int n_in,
                              void* d_out, int out_size, void* d_ws, size_t ws_size,
                              hipStream_t stream) {
  const float* x  = (const float*)d_in[0];
  const float* rw = (const float*)d_in[1];
  const float* rb = (const float*)d_in[2];
  const float* w1 = (const float*)d_in[3];
  const float* b1 = (const float*)d_in[4];
  const float* w2 = (const float*)d_in[5];
  const float* b2 = (const float*)d_in[6];
  float* out = (float*)d_out;
  char* ws = (char*)d_ws;

  unsigned short* w1t = (unsigned short*)(ws + W1T_OFF);
  unsigned short* w2t = (unsigned short*)(ws + W2T_OFF);
  unsigned short* h   = (unsigned short*)(ws + H_OFF);
  unsigned short* xb  = (unsigned short*)(ws + XB_OFF);
  int* cnt   = (int*)(ws + CNT_OFF);
  int* plist = (int*)(ws + PLIST_OFF);
  float* pwt = (float*)(ws + PW_OFF);
  int* tops  = (int*)(ws + TOPS_OFF);
  float* w0f = (float*)(ws + W0_OFF);

  hipLaunchKernelGGL(zero_cnt_k, dim3(1), dim3(64), 0, stream, cnt);
  hipLaunchKernelGGL(zero_out_k, dim3(16384), dim3(256), 0, stream, (float4*)out);
  hipLaunchKernelGGL(xcast_k, dim3(NTOK * HIDDEN / 8 / 256), dim3(256), 0, stream, x, xb);
  hipLaunchKernelGGL(transpose_cast_k, dim3(FF / 32, HIDDEN / 32, NEXP), dim3(256), 0, stream,
                     w1, w1t, HIDDEN, FF);
  hipLaunchKernelGGL(transpose_cast_k, dim3(HIDDEN / 32, FF / 32, NEXP), dim3(256), 0, stream,
                     w2, w2t, FF, HIDDEN);
  hipLaunchKernelGGL(router_k, dim3(NTOK / 4), dim3(256), 0, stream, x, rw, rb, tops, w0f);
  hipLaunchKernelGGL(scatter_k, dim3(NTOK / 256), dim3(256), 0, stream, tops, w0f, cnt, plist, pwt);
  hipLaunchKernelGGL(ffn_k<1>, dim3(128, FF / 128, NEXP), dim3(256), 0, stream,
                     xb, w1t, b1, (const unsigned short*)nullptr, h, (float*)nullptr,
                     cnt, plist, pwt);
  hipLaunchKernelGGL(ffn_k<2>, dim3(128, HIDDEN / 128, NEXP), dim3(256), 0, stream,
                     xb, w2t, b2, h, (unsigned short*)nullptr, out,
                     cnt, plist, pwt);
}

// Round 3
// 613.205 us; speedup vs baseline: 1.7785x; 1.1089x over previous
//
#include <hip/hip_runtime.h>

#define HIDDEN 1024
#define FF 2048
#define NEXP 8
#define NTOK 16384
#define NPAIR (2 * NTOK)

typedef short short8 __attribute__((ext_vector_type(8)));
typedef float f32x4 __attribute__((ext_vector_type(4)));

// fp32 -> bf16 bits, round-to-nearest-even
__device__ __forceinline__ unsigned short f2b(float f) {
  union { float f; unsigned int u; } v; v.f = f;
  unsigned int u = v.u;
  return (unsigned short)((u + 0x7fffu + ((u >> 16) & 1u)) >> 16);
}

// async global->LDS, 16B per lane. LDS dest = wave-uniform base + lane*16.
__device__ __forceinline__ void gload16(const unsigned short* g, unsigned short* l) {
  __builtin_amdgcn_global_load_lds(
      (const __attribute__((address_space(1))) unsigned int*)g,
      (__attribute__((address_space(3))) unsigned int*)l,
      16, 0, 0);
}

// ---------------- workspace layout (bytes) ----------------
#define W1T_OFF 0ull                                                      // [E][FF][HIDDEN] bf16, 32MB
#define W2T_OFF (W1T_OFF + (unsigned long long)NEXP * FF * HIDDEN * 2)    // [E][HIDDEN][FF] bf16, 32MB
#define H_OFF   (W2T_OFF + (unsigned long long)NEXP * HIDDEN * FF * 2)    // [NPAIR][FF] bf16, 128MB
#define XB_OFF  (H_OFF + (unsigned long long)NPAIR * FF * 2)              // [NTOK][HIDDEN] bf16, 32MB
#define CNT_OFF (XB_OFF + (unsigned long long)NTOK * HIDDEN * 2)          // [E] int
#define PLIST_OFF (CNT_OFF + 256ull)                                      // [E][NTOK] int
#define PW_OFF    (PLIST_OFF + (unsigned long long)NEXP * NTOK * 4)       // [NPAIR] float
#define TOPS_OFF  (PW_OFF + (unsigned long long)NPAIR * 4)                // [NTOK] int
#define W0_OFF    (TOPS_OFF + (unsigned long long)NTOK * 4)               // [NTOK] float

__global__ void zero_out_k(float4* __restrict__ out) {
  out[(size_t)blockIdx.x * 256 + threadIdx.x] = float4{0.f, 0.f, 0.f, 0.f};
}

__global__ void zero_cnt_k(int* __restrict__ cnt) {
  if (threadIdx.x < NEXP) cnt[threadIdx.x] = 0;
}

// x fp32 -> bf16, 8 elems/thread
__global__ void xcast_k(const float* __restrict__ x, unsigned short* __restrict__ xb) {
  const size_t i = ((size_t)blockIdx.x * 256 + threadIdx.x) * 8;
  float4 a = reinterpret_cast<const float4*>(x + i)[0];
  float4 b = reinterpret_cast<const float4*>(x + i)[1];
  short8 v;
  v[0] = (short)f2b(a.x); v[1] = (short)f2b(a.y); v[2] = (short)f2b(a.z); v[3] = (short)f2b(a.w);
  v[4] = (short)f2b(b.x); v[5] = (short)f2b(b.y); v[6] = (short)f2b(b.z); v[7] = (short)f2b(b.w);
  *reinterpret_cast<short8*>(xb + i) = v;
}

// in: [E][R][C] f32  ->  out: [E][C][R] bf16
__global__ void transpose_cast_k(const float* __restrict__ in,
                                 unsigned short* __restrict__ out,
                                 int R, int C) {
  __shared__ float tile[32][33];
  const size_t eoff = (size_t)blockIdx.z * R * C;
  const float* inp = in + eoff;
  unsigned short* outp = out + eoff;
  const int c = threadIdx.x & 31;
  const int r0 = threadIdx.x >> 5;
  const int gr = blockIdx.y * 32, gc = blockIdx.x * 32;
#pragma unroll
  for (int i = 0; i < 4; i++) {
    int r = r0 + i * 8;
    tile[r][c] = inp[(size_t)(gr + r) * C + gc + c];
  }
  __syncthreads();
#pragma unroll
  for (int i = 0; i < 4; i++) {
    int r = r0 + i * 8;
    outp[(size_t)(gc + r) * R + gr + c] = f2b(tile[c][r]);
  }
}

// one wave per token: logits over 8 experts, top-2, renorm. NO atomics.
__global__ void router_k(const float* __restrict__ x, const float* __restrict__ rw,
                         const float* __restrict__ rb, int* __restrict__ tops,
                         float* __restrict__ w0f) {
  const int wid = threadIdx.x >> 6;
  const int lane = threadIdx.x & 63;
  const int t = blockIdx.x * 4 + wid;
  const float* xr = x + (size_t)t * HIDDEN;
  float acc[8];
#pragma unroll
  for (int e = 0; e < 8; e++) acc[e] = 0.f;
#pragma unroll
  for (int i = 0; i < 16; i++) {
    int hh = lane + 64 * i;
    float xv = xr[hh];
    const float4* rwp = reinterpret_cast<const float4*>(rw + (size_t)hh * 8);
    float4 a = rwp[0], b = rwp[1];
    acc[0] += xv * a.x; acc[1] += xv * a.y; acc[2] += xv * a.z; acc[3] += xv * a.w;
    acc[4] += xv * b.x; acc[5] += xv * b.y; acc[6] += xv * b.z; acc[7] += xv * b.w;
  }
#pragma unroll
  for (int off = 32; off; off >>= 1) {
#pragma unroll
    for (int e = 0; e < 8; e++) acc[e] += __shfl_xor(acc[e], off);
  }
  if (lane == 0) {
#pragma unroll
    for (int e = 0; e < 8; e++) acc[e] += rb[e];
    int i0 = 0; float m0 = acc[0];
#pragma unroll
    for (int e = 1; e < 8; e++) if (acc[e] > m0) { m0 = acc[e]; i0 = e; }
    int i1 = -1; float m1 = -1e30f;
#pragma unroll
    for (int e = 0; e < 8; e++) if (e != i0 && acc[e] > m1) { m1 = acc[e]; i1 = e; }
    float w0 = 1.f / (1.f + __expf(m1 - m0));
    tops[t] = i0 | (i1 << 4);
    w0f[t] = w0;
  }
}

// block-aggregated scatter: 256 tokens/block, LDS histogram, 8 global atomics/block
__global__ __launch_bounds__(256)
void scatter_k(const int* __restrict__ tops, const float* __restrict__ w0f,
               int* __restrict__ cnt, int* __restrict__ plist, float* __restrict__ pw) {
  __shared__ int lcnt[NEXP];
  __shared__ int lbase[NEXP];
  const int tid = threadIdx.x;
  const int t = blockIdx.x * 256 + tid;
  if (tid < NEXP) lcnt[tid] = 0;
  __syncthreads();
  const int packed = tops[t];
  const int i0 = packed & 15, i1 = packed >> 4;
  const float w0 = w0f[t];
  const int s0 = atomicAdd(&lcnt[i0], 1);
  const int s1 = atomicAdd(&lcnt[i1], 1);
  __syncthreads();
  if (tid < NEXP) lbase[tid] = atomicAdd(&cnt[tid], lcnt[tid]);
  __syncthreads();
  plist[i0 * NTOK + lbase[i0] + s0] = 2 * t;
  plist[i1 * NTOK + lbase[i1] + s1] = 2 * t + 1;
  pw[2 * t] = w0;
  pw[2 * t + 1] = 1.f - w0;
}

// Grouped GEMM, m97 structure: 128x128 tile, BK=32, linear LDS, global_load_lds.
// PHASE 1: h[pair] = relu(xb[token] @ w1t[e]^T + b1[e])  (K=1024,N=2048)
// PHASE 2: out[token] += pw[pair] * (h[pair] @ w2t[e]^T + b2[e]) (K=2048,N=1024)
template <int PHASE>
__global__ __launch_bounds__(256)
void ffn_k(const unsigned short* __restrict__ xb, const unsigned short* __restrict__ wT,
           const float* __restrict__ bias, const unsigned short* __restrict__ hin,
           unsigned short* __restrict__ hout, float* __restrict__ out,
           const int* __restrict__ cnt, const int* __restrict__ plist,
           const float* __restrict__ pw) {
  constexpr int K = (PHASE == 1) ? HIDDEN : FF;
  constexpr int N = (PHASE == 1) ? FF : HIDDEN;

  const int e = blockIdx.z;
  const int mcnt = cnt[e];
  const int m0g = blockIdx.x * 128;
  if (m0g >= mcnt) return;
  const int n0g = blockIdx.y * 128;
  const int mrem = mcnt - m0g;  // valid rows (cap via comparisons below)

  // linear, unpadded: rows of 32 shorts (64 B). 8 KB each.
  __shared__ alignas(16) unsigned short As[128][32];
  __shared__ alignas(16) unsigned short Bs[128][32];
  __shared__ int rowpair[128];

  const int tid = threadIdx.x;
  if (tid < 128) rowpair[tid] = (tid < mrem) ? plist[e * NTOK + m0g + tid] : -1;
  __syncthreads();

  const int wid = tid >> 6;
  const int lane = tid & 63;

  // ---- staging pointer setup ----
  // chunk c (0..7) covers LDS bytes [c*1024, c*1024+1024) = rows [c*16, c*16+16).
  // lane l handles row c*16 + (l>>2), 16B slot (l&3). wave w owns chunks {w, w+4}.
  const int slot = lane & 3;
  const int rsub = lane >> 2;
  const unsigned short* wTe = wT + (size_t)e * N * K;

  const unsigned short* gA[2];
  const unsigned short* gB[2];
#pragma unroll
  for (int i = 0; i < 2; i++) {
    const int c = wid + i * 4;
    const int row = c * 16 + rsub;
    int p = rowpair[row];
    if (p < 0) p = 0;  // dummy valid row; its acc rows are never written
    const unsigned short* abase;
    if constexpr (PHASE == 1) abase = xb + (size_t)(p >> 1) * HIDDEN;
    else                      abase = hin + (size_t)p * FF;
    gA[i] = abase + slot * 8;
    gB[i] = wTe + (size_t)(n0g + row) * K + slot * 8;
  }

  const int wr = (wid >> 1) * 64;
  const int wc = (wid & 1) * 64;
  const int fr = lane & 15;
  const int fg = lane >> 4;

  f32x4 acc[4][4];
#pragma unroll
  for (int i = 0; i < 4; i++)
#pragma unroll
    for (int j = 0; j < 4; j++) acc[i][j] = f32x4{0.f, 0.f, 0.f, 0.f};

  for (int kt = 0; kt < K; kt += 32) {
    // ---- issue async staging (4 x global_load_lds_dwordx4 per wave) ----
#pragma unroll
    for (int i = 0; i < 2; i++) {
      const int c = wid + i * 4;
      gload16(gA[i] + kt, &As[c * 16][0]);
      gload16(gB[i] + kt, &Bs[c * 16][0]);
    }
    __syncthreads();  // drains vmcnt(0): tile resident

    short8 af[4], bf[4];
#pragma unroll
    for (int mi = 0; mi < 4; mi++) af[mi] = *(const short8*)&As[wr + mi * 16 + fr][fg * 8];
#pragma unroll
    for (int ni = 0; ni < 4; ni++) bf[ni] = *(const short8*)&Bs[wc + ni * 16 + fr][fg * 8];
#pragma unroll
    for (int mi = 0; mi < 4; mi++)
#pragma unroll
      for (int ni = 0; ni < 4; ni++)
        acc[mi][ni] = __builtin_amdgcn_mfma_f32_16x16x32_bf16(af[mi], bf[ni], acc[mi][ni], 0, 0, 0);
    __syncthreads();  // protect LDS before next-iter overwrite
  }

  // ---- epilogue ----
  float bv[4];
#pragma unroll
  for (int ni = 0; ni < 4; ni++) bv[ni] = bias[(size_t)e * N + n0g + wc + ni * 16 + fr];

#pragma unroll
  for (int mi = 0; mi < 4; mi++) {
#pragma unroll
    for (int r = 0; r < 4; r++) {
      int m = wr + mi * 16 + fg * 4 + r;
      if (m >= mrem) continue;
      int p = rowpair[m];
      if constexpr (PHASE == 1) {
        unsigned short* hr = hout + (size_t)p * FF + n0g;
#pragma unroll
        for (int ni = 0; ni < 4; ni++) {
          float v = acc[mi][ni][r] + bv[ni];
          hr[wc + ni * 16 + fr] = f2b(fmaxf(v, 0.f));
        }
      } else {
        float wgt = pw[p];
        float* orow = out + (size_t)(p >> 1) * HIDDEN + n0g;
#pragma unroll
        for (int ni = 0; ni < 4; ni++) {
          float v = (acc[mi][ni][r] + bv[ni]) * wgt;
          atomicAdd(&orow[wc + ni * 16 + fr], v);
        }
      }
    }
  }
}

extern "C" void kernel_launch(void* const* d_in, const int* in_sizes, int n_in,
                              void* d_out, int out_size, void* d_ws, size_t ws_size,
                              hipStream_t stream) {
  const float* x  = (const float*)d_in[0];
  const float* rw = (const float*)d_in[1];
  const float* rb = (const float*)d_in[2];
  const float* w1 = (const float*)d_in[3];
  const float* b1 = (const float*)d_in[4];
  const float* w2 = (const float*)d_in[5];
  const float* b2 = (const float*)d_in[6];
  float* out = (float*)d_out;
  char* ws = (char*)d_ws;

  unsigned short* w1t = (unsigned short*)(ws + W1T_OFF);
  unsigned short* w2t = (unsigned short*)(ws + W2T_OFF);
  unsigned short* h   = (unsigned short*)(ws + H_OFF);
  unsigned short* xb  = (unsigned short*)(ws + XB_OFF);
  int* cnt   = (int*)(ws + CNT_OFF);
  int* plist = (int*)(ws + PLIST_OFF);
  float* pwt = (float*)(ws + PW_OFF);
  int* tops  = (int*)(ws + TOPS_OFF);
  float* w0f = (float*)(ws + W0_OFF);

  hipLaunchKernelGGL(zero_cnt_k, dim3(1), dim3(64), 0, stream, cnt);
  hipLaunchKernelGGL(zero_out_k, dim3(16384), dim3(256), 0, stream, (float4*)out);
  hipLaunchKernelGGL(xcast_k, dim3(NTOK * HIDDEN / 8 / 256), dim3(256), 0, stream, x, xb);
  hipLaunchKernelGGL(transpose_cast_k, dim3(FF / 32, HIDDEN / 32, NEXP), dim3(256), 0, stream,
                     w1, w1t, HIDDEN, FF);
  hipLaunchKernelGGL(transpose_cast_k, dim3(HIDDEN / 32, FF / 32, NEXP), dim3(256), 0, stream,
                     w2, w2t, FF, HIDDEN);
  hipLaunchKernelGGL(router_k, dim3(NTOK / 4), dim3(256), 0, stream, x, rw, rb, tops, w0f);
  hipLaunchKernelGGL(scatter_k, dim3(NTOK / 256), dim3(256), 0, stream, tops, w0f, cnt, plist, pwt);
  hipLaunchKernelGGL(ffn_k<1>, dim3(128, FF / 128, NEXP), dim3(256), 0, stream,
                     xb, w1t, b1, (const unsigned short*)nullptr, h, (float*)nullptr,
                     cnt, plist, pwt);
  hipLaunchKernelGGL(ffn_k<2>, dim3(128, HIDDEN / 128, NEXP), dim3(256), 0, stream,
                     xb, w2t, b2, h, (unsigned short*)nullptr, out,
                     cnt, plist, pwt);
}